// Round 4
// baseline (1779.143 us; speedup 1.0000x reference)
//
#include <hip/hip_runtime.h>
#include <hip/hip_bf16.h>

// DCNConv pipeline, MI355X round 3: deform conv -> bf16 MFMA implicit GEMM.
//
// Shapes: x[8,128,160,160] -> conv3x3 s2 p1 + BN + SiLU -> h[8,256,80,80]
//         h -> conv3x3 s1 p1 (+bias) -> offset[8,18,80,80]
//         deform_conv3x3(h, offset, dconv_w) -> y[8,256,80,80]
//         BN + SiLU -> out (fp32)
//
// conv1 GEMM:  M=256 oc, N=51200 pos, K=1152 (c*9+tap),   mfma 16x16x32 bf16.
// dconv GEMM:  M=256 oc, N=51200 pos, K=2304 (tap*256+c), mfma 16x16x32 bf16.
//   tap-major K => each BK=32 chunk is one tap x 32 channels; bilinear corner
//   idx/weights depend only on (pixel,tap) -> precomputed once per block.
// Workspace layout:
//   [0)            h bf16   8*256*6400      = 26,214,400 B
//   [26,214,400)   offset fp32 8*18*6400    =  3,686,400 B
//   [29,900,800)   wb2 bf16 [256oc][2304kk] =  1,179,648 B  (dconv w, tap-major)
//   [31,080,448)   wb  bf16 [256oc][1152k]  =    589,824 B  (conv1 w)

typedef __hip_bfloat16 bf16;
typedef __attribute__((ext_vector_type(8))) short short8;
typedef __attribute__((ext_vector_type(4))) float float4v;

#define EPSBN 1e-5f

__device__ __forceinline__ float bf2f(bf16 x){ return __bfloat162float(x); }
__device__ __forceinline__ float silu_(float x){ return x / (1.f + __expf(-x)); }
__device__ __forceinline__ unsigned short f2bf_bits(float f){
    union { float f; unsigned u; } uf; uf.f = f;
    unsigned r = uf.u + 0x7fff + ((uf.u >> 16) & 1);   // RNE (finite inputs)
    return (unsigned short)(r >> 16);
}

// ---------------------------------------------------------------------------
// K0a: dconv_w [256oc][256c][9tap] fp32 -> wb2 bf16 [256oc][2304], kk = tap*256+c.
__global__ __launch_bounds__(256) void k_wdprep(const float* __restrict__ w, bf16* __restrict__ wb2)
{
    int idx = blockIdx.x * 256 + threadIdx.x;      // 589,824 total
    if (idx >= 256 * 2304) return;
    int oc  = idx / 2304;
    int r   = idx - oc * 2304;
    int tap = r >> 8;
    int c   = r & 255;
    wb2[idx] = __float2bfloat16(w[(oc * 256 + c) * 9 + tap]);
}

// K0b: conv1 weights fp32 -> bf16, natural [oc][c][tap] flatten == GEMM [oc][k].
__global__ __launch_bounds__(256) void k_wprep(const float* __restrict__ w, bf16* __restrict__ wb)
{
    int idx = blockIdx.x * 256 + threadIdx.x;      // 294,912 total
    if (idx >= 256 * 1152) return;
    wb[idx] = __float2bfloat16(w[idx]);
}

// ---------------------------------------------------------------------------
// K1: conv1 (3x3 s2 p1) + BN1 + SiLU via MFMA implicit GEMM (round-2, unchanged).
__global__ __launch_bounds__(256) void k_conv1(
    const float* __restrict__ x, const bf16* __restrict__ wb,
    const float* __restrict__ g, const float* __restrict__ bb,
    const float* __restrict__ mm, const float* __restrict__ vv,
    bf16* __restrict__ h)
{
    __shared__ short A_lds[256 * 40];              // 20,480 B
    __shared__ short B_lds[64 * 40];               //  5,120 B
    __shared__ float sc_s[256], sh_s[256];         //  2,048 B

    const int tid  = threadIdx.x;
    const int b    = blockIdx.x / 100;             // 800 blocks: 100 per image
    const int pix0 = (blockIdx.x % 100) * 64;
    const float* xb = x + b * (128 * 25600);

    {   // per-oc fused BN constants (tid == oc)
        float scv = g[tid] * rsqrtf(vv[tid] + EPSBN);
        sc_s[tid] = scv;
        sh_s[tid] = bb[tid] - mm[tid] * scv;
    }

    const int k_in = tid & 31;
    const int prow = tid >> 5;                     // 0..7
    int oh8[8], ow8[8];
    #pragma unroll
    for (int p = 0; p < 8; p++){
        int pix = pix0 + prow + p * 8;
        oh8[p] = pix / 80; ow8[p] = pix % 80;
    }

    const int wv   = tid >> 6;
    const int lane = tid & 63;
    const int lrow = lane & 15;
    const int quad = lane >> 4;

    float4v acc[4][4];
    #pragma unroll
    for (int i = 0; i < 4; i++)
        #pragma unroll
        for (int j = 0; j < 4; j++)
            acc[i][j] = (float4v){0.f, 0.f, 0.f, 0.f};

    for (int kc = 0; kc < 36; kc++){
        const int k0 = kc * 32;
        __syncthreads();

        #pragma unroll
        for (int p2 = 0; p2 < 4; p2++){
            int idx = p2 * 256 + tid;
            int oc  = idx >> 2;
            int kq  = idx & 3;
            *reinterpret_cast<uint4*>(&A_lds[oc * 40 + kq * 8]) =
                *reinterpret_cast<const uint4*>(wb + oc * 1152 + k0 + kq * 8);
        }

        {
            int kk  = k0 + k_in;
            int c   = kk / 9;
            int tap = kk - 9 * c;
            int kh  = tap / 3 - 1;
            int kw  = tap - 3 * (tap / 3) - 1;
            const float* xc = xb + c * 25600;
            #pragma unroll
            for (int p = 0; p < 8; p++){
                int ih = 2 * oh8[p] + kh;
                int iw = 2 * ow8[p] + kw;
                float v = 0.f;
                if ((ih | iw) >= 0) v = xc[ih * 160 + iw];
                B_lds[(prow + p * 8) * 40 + k_in] = (short)f2bf_bits(v);
            }
        }
        __syncthreads();

        short8 af[4], bfv[4];
        #pragma unroll
        for (int i = 0; i < 4; i++){
            int row = wv * 64 + i * 16 + lrow;
            af[i] = *reinterpret_cast<const short8*>(&A_lds[row * 40 + quad * 8]);
        }
        #pragma unroll
        for (int j = 0; j < 4; j++){
            bfv[j] = *reinterpret_cast<const short8*>(&B_lds[(j * 16 + lrow) * 40 + quad * 8]);
        }
        #pragma unroll
        for (int i = 0; i < 4; i++)
            #pragma unroll
            for (int j = 0; j < 4; j++)
                acc[i][j] = __builtin_amdgcn_mfma_f32_16x16x32_bf16(af[i], bfv[j], acc[i][j], 0, 0, 0);
    }

    #pragma unroll
    for (int i = 0; i < 4; i++){
        #pragma unroll
        for (int r = 0; r < 4; r++){
            int oc = wv * 64 + i * 16 + quad * 4 + r;
            float scv = sc_s[oc], shv = sh_s[oc];
            #pragma unroll
            for (int j = 0; j < 4; j++){
                int pix = pix0 + j * 16 + lrow;
                float y = acc[i][j][r] * scv + shv;
                h[(b * 256 + oc) * 6400 + pix] = __float2bfloat16(silu_(y));
            }
        }
    }
}

// ---------------------------------------------------------------------------
// K2: offset conv (3x3, stride 1, pad 1, +bias): h[8,256,80,80] -> off[8,18,80,80] fp32.
__global__ __launch_bounds__(256) void k_off(
    const bf16* __restrict__ h, const float* __restrict__ w,
    const float* __restrict__ bias, float* __restrict__ off)
{
    __shared__ float ws_[256 * 9];
    const int tid = threadIdx.x;
    const int blk = blockIdx.x;                    // 3600 = 8*18*25
    const int boc = blk / 25;
    const int oc  = boc % 18;
    const int b   = boc / 18;
    const int pix = (blk % 25) * 256 + tid;

    for (int i = tid; i < 2304; i += 256) ws_[i] = w[oc * 2304 + i];
    __syncthreads();

    const int oh = pix / 80, ow = pix % 80;
    int ofs[9]; float msk[9];
    #pragma unroll
    for (int tap = 0; tap < 9; tap++){
        int kh = tap / 3, kw = tap % 3;
        int ih = oh + kh - 1, iw = ow + kw - 1;
        bool val = (ih >= 0) && (ih < 80) && (iw >= 0) && (iw < 80);
        int ihc = min(max(ih, 0), 79), iwc = min(max(iw, 0), 79);
        ofs[tap] = ihc * 80 + iwc;
        msk[tap] = val ? 1.f : 0.f;
    }

    const bf16* hb = h + b * (256 * 6400);
    float acc = bias[oc];
    for (int c = 0; c < 256; c++){
        const bf16*  hc = hb + c * 6400;
        const float* wc = &ws_[c * 9];
        #pragma unroll
        for (int tap = 0; tap < 9; tap++){
            acc += bf2f(hc[ofs[tap]]) * msk[tap] * wc[tap];
        }
    }
    off[boc * 6400 + pix] = acc;
}

// ---------------------------------------------------------------------------
// K3: deformable conv 3x3 + BN2 + SiLU via MFMA implicit GEMM.
// Block: 256 threads = 4 waves; tile 256oc x 64pos; K = 2304 tap-major, 72 chunks.
// Corner idx/weights precomputed per (tap,pos) in LDS (576 int4 + float4).
// Stage B per chunk (one tap, 32 channels): thread = fixed c, 8 positions,
// 4 gathered bf16 corner loads + fp32 bilinear dot -> bf16 into B_lds.
__global__ __launch_bounds__(256) void k_dconv(
    const bf16* __restrict__ h, const float* __restrict__ off,
    const bf16* __restrict__ wb2,
    const float* __restrict__ g, const float* __restrict__ bb,
    const float* __restrict__ mm, const float* __restrict__ vv,
    float* __restrict__ out)
{
    __shared__ short  A_lds[256 * 40];             // 20,480 B
    __shared__ short  B_lds[64 * 40];              //  5,120 B
    __shared__ int4   sidx4[576];                  //  9,216 B
    __shared__ float4 swt4 [576];                  //  9,216 B
    __shared__ float  sc_s[256], sh_s[256];        //  2,048 B

    const int tid  = threadIdx.x;
    const int b    = blockIdx.x / 100;             // 800 blocks: 100 per image
    const int pix0 = (blockIdx.x % 100) * 64;
    const bf16* hb = h + b * (256 * 6400);

    {   // per-oc fused BN constants (tid == oc)
        float scv = g[tid] * rsqrtf(vv[tid] + EPSBN);
        sc_s[tid] = scv;
        sh_s[tid] = bb[tid] - mm[tid] * scv;
    }

    // corner precompute: e = tap*64 + t
    for (int e = tid; e < 576; e += 256){
        int t = e & 63, k = e >> 6;
        int pix = pix0 + t;
        int oh = pix / 80, ow = pix % 80;
        int kh = k / 3, kw = k % 3;
        float oy = off[(b * 18 + 2 * k    ) * 6400 + pix];
        float ox = off[(b * 18 + 2 * k + 1) * 6400 + pix];
        float py = (float)(oh + kh - 1) + oy;
        float px = (float)(ow + kw - 1) + ox;
        float y0f = floorf(py), x0f = floorf(px);
        float wy1 = py - y0f,  wx1 = px - x0f;
        int y0 = (int)y0f, x0 = (int)x0f;
        int   ii[4]; float ww[4];
        #pragma unroll
        for (int cy = 0; cy < 2; cy++){
            int   yy = y0 + cy;
            float wy = cy ? wy1 : 1.f - wy1;
            bool  vy = (yy >= 0) && (yy < 80);
            int   yc = min(max(yy, 0), 79);
            #pragma unroll
            for (int cx = 0; cx < 2; cx++){
                int   xx = x0 + cx;
                float wx = cx ? wx1 : 1.f - wx1;
                bool  vx = (xx >= 0) && (xx < 80);
                int   xc = min(max(xx, 0), 79);
                int ci = cy * 2 + cx;
                ii[ci] = yc * 80 + xc;
                ww[ci] = (vy && vx) ? wy * wx : 0.f;
            }
        }
        sidx4[e] = make_int4(ii[0], ii[1], ii[2], ii[3]);
        swt4 [e] = make_float4(ww[0], ww[1], ww[2], ww[3]);
    }

    const int k_in = tid & 31;
    const int prow = tid >> 5;                     // 0..7
    const int wv   = tid >> 6;
    const int lane = tid & 63;
    const int lrow = lane & 15;
    const int quad = lane >> 4;

    float4v acc[4][4];
    #pragma unroll
    for (int i = 0; i < 4; i++)
        #pragma unroll
        for (int j = 0; j < 4; j++)
            acc[i][j] = (float4v){0.f, 0.f, 0.f, 0.f};

    for (int kc = 0; kc < 72; kc++){
        __syncthreads();                           // kc=0: guards sidx4/swt4; else prev frag reads

        // stage A: 256oc x 32k from wb2 (L2-resident, 1.2 MB)
        #pragma unroll
        for (int p2 = 0; p2 < 4; p2++){
            int idx = p2 * 256 + tid;
            int oc  = idx >> 2;
            int kq  = idx & 3;
            *reinterpret_cast<uint4*>(&A_lds[oc * 40 + kq * 8]) =
                *reinterpret_cast<const uint4*>(wb2 + oc * 2304 + kc * 32 + kq * 8);
        }

        // stage B: bilinear-sample 32c x 64pos for this chunk's tap
        {
            const int tap = kc >> 3;
            const int c   = ((kc & 7) << 5) + k_in;
            const bf16* hc = hb + c * 6400;
            #pragma unroll
            for (int p = 0; p < 8; p++){
                int t = prow + p * 8;
                int e = tap * 64 + t;
                int4   ip = sidx4[e];
                float4 wp = swt4[e];
                float s = wp.x * bf2f(hc[ip.x]) + wp.y * bf2f(hc[ip.y])
                        + wp.z * bf2f(hc[ip.z]) + wp.w * bf2f(hc[ip.w]);
                B_lds[t * 40 + k_in] = (short)f2bf_bits(s);
            }
        }
        __syncthreads();

        short8 af[4], bfv[4];
        #pragma unroll
        for (int i = 0; i < 4; i++){
            int row = wv * 64 + i * 16 + lrow;
            af[i] = *reinterpret_cast<const short8*>(&A_lds[row * 40 + quad * 8]);
        }
        #pragma unroll
        for (int j = 0; j < 4; j++){
            bfv[j] = *reinterpret_cast<const short8*>(&B_lds[(j * 16 + lrow) * 40 + quad * 8]);
        }
        #pragma unroll
        for (int i = 0; i < 4; i++)
            #pragma unroll
            for (int j = 0; j < 4; j++)
                acc[i][j] = __builtin_amdgcn_mfma_f32_16x16x32_bf16(af[i], bfv[j], acc[i][j], 0, 0, 0);
    }

    // epilogue: D col = lane&15 (pos), row = quad*4 + reg (oc); fused BN2+SiLU
    #pragma unroll
    for (int i = 0; i < 4; i++){
        #pragma unroll
        for (int r = 0; r < 4; r++){
            int oc = wv * 64 + i * 16 + quad * 4 + r;
            float scv = sc_s[oc], shv = sh_s[oc];
            #pragma unroll
            for (int j = 0; j < 4; j++){
                int pix = pix0 + j * 16 + lrow;
                out[(b * 256 + oc) * 6400 + pix] = silu_(acc[i][j][r] * scv + shv);
            }
        }
    }
}

// ---------------------------------------------------------------------------
extern "C" void kernel_launch(void* const* d_in, const int* in_sizes, int n_in,
                              void* d_out, int out_size, void* d_ws, size_t ws_size,
                              hipStream_t stream)
{
    (void)in_sizes; (void)n_in; (void)out_size; (void)ws_size;

    const float* x  = (const float*)d_in[0];
    const float* w1 = (const float*)d_in[1];
    const float* g1 = (const float*)d_in[2];
    const float* b1 = (const float*)d_in[3];
    const float* m1 = (const float*)d_in[4];
    const float* v1 = (const float*)d_in[5];
    const float* wo = (const float*)d_in[6];
    const float* bo = (const float*)d_in[7];
    const float* wd = (const float*)d_in[8];
    const float* g2 = (const float*)d_in[9];
    const float* b2 = (const float*)d_in[10];
    const float* m2 = (const float*)d_in[11];
    const float* v2 = (const float*)d_in[12];
    float* outp = (float*)d_out;

    char*  wsb  = (char*)d_ws;
    bf16*  hbuf = (bf16*) wsb;                               // 26,214,400 B
    float* obuf = (float*)(wsb + 26214400);                  //  3,686,400 B
    bf16*  wb2b = (bf16*) (wsb + 26214400 + 3686400);        //  1,179,648 B
    bf16*  wbb  = (bf16*) (wsb + 26214400 + 3686400 + 1179648); // 589,824 B

    hipLaunchKernelGGL(k_wdprep, dim3(2304), dim3(256), 0, stream, wd, wb2b);
    hipLaunchKernelGGL(k_wprep,  dim3(1152), dim3(256), 0, stream, w1, wbb);
    hipLaunchKernelGGL(k_conv1,  dim3(800),  dim3(256), 0, stream, x, wbb, g1, b1, m1, v1, hbuf);
    hipLaunchKernelGGL(k_off,    dim3(3600), dim3(256), 0, stream, hbuf, wo, bo, obuf);
    hipLaunchKernelGGL(k_dconv,  dim3(800),  dim3(256), 0, stream, hbuf, obuf, wb2b, g2, b2, m2, v2, outp);
}

// Round 6
// 870.966 us; speedup vs baseline: 2.0427x; 2.0427x over previous
//
#include <hip/hip_runtime.h>
#include <hip/hip_bf16.h>

// DCNConv pipeline, MI355X round 5: BISECT round-4's 0.498 absmax failure.
// Primary path (needs 57.9 MB ws): round-4 NHWC MFMA k_dconv (suspect) +
// validated round-3 scalar k_off (reads NCHW hC) + conv1 writing BOTH layouts.
// Fallback path (ws < 57.9 MB): exact round-3 validated configuration.
//
// Primary ws layout:
//   [0)          hN  bf16 [8][6400pix][256c] = 26,214,400 B
//   [26,214,400) hC  bf16 [8][256c][6400pix] = 26,214,400 B
//   [52,428,800) off fp32 [8][18][6400]      =  3,686,400 B
//   [56,115,200) wb2 bf16 [256][2304]        =  1,179,648 B (dconv w, tap-major)
//   [57,294,848) wb  bf16 [256][1152]        =    589,824 B (conv1 w)
// Fallback ws layout (round-3): hC@0, off@26214400, wb2@29900800, wb@31080448.

typedef __hip_bfloat16 bf16;
typedef __attribute__((ext_vector_type(8))) short short8;
typedef __attribute__((ext_vector_type(4))) float float4v;

#define EPSBN 1e-5f

__device__ __forceinline__ float bf2f(bf16 x){ return __bfloat162float(x); }
__device__ __forceinline__ float bits2f(unsigned short u){ return __uint_as_float(((unsigned)u) << 16); }
__device__ __forceinline__ float silu_(float x){ return x / (1.f + __expf(-x)); }
__device__ __forceinline__ unsigned short f2bf_bits(float f){
    union { float f; unsigned u; } uf; uf.f = f;
    unsigned r = uf.u + 0x7fff + ((uf.u >> 16) & 1);   // RNE (finite inputs)
    return (unsigned short)(r >> 16);
}

// ---------------------------------------------------------------------------
// K0a: dconv_w [256oc][256c][9tap] fp32 -> wb2 bf16 [256oc][2304], kk = tap*256+c.
__global__ __launch_bounds__(256) void k_wdprep(const float* __restrict__ w, bf16* __restrict__ wb2)
{
    int idx = blockIdx.x * 256 + threadIdx.x;
    if (idx >= 256 * 2304) return;
    int oc  = idx / 2304;
    int r   = idx - oc * 2304;
    int tap = r >> 8;
    int c   = r & 255;
    wb2[idx] = __float2bfloat16(w[(oc * 256 + c) * 9 + tap]);
}

// K0b: conv1 weights fp32 -> bf16.
__global__ __launch_bounds__(256) void k_wprep(const float* __restrict__ w, bf16* __restrict__ wb)
{
    int idx = blockIdx.x * 256 + threadIdx.x;
    if (idx >= 256 * 1152) return;
    wb[idx] = __float2bfloat16(w[idx]);
}

// ---------------------------------------------------------------------------
// K1 (primary): conv1 MFMA implicit GEMM, writes BOTH hN (NHWC) and hC (NCHW).
__global__ __launch_bounds__(256) void k_conv1_dual(
    const float* __restrict__ x, const bf16* __restrict__ wb,
    const float* __restrict__ g, const float* __restrict__ bb,
    const float* __restrict__ mm, const float* __restrict__ vv,
    bf16* __restrict__ hN, bf16* __restrict__ hC)
{
    __shared__ short A_lds[256 * 40];
    __shared__ short B_lds[64 * 40];
    __shared__ float sc_s[256], sh_s[256];

    const int tid  = threadIdx.x;
    const int b    = blockIdx.x / 100;
    const int pix0 = (blockIdx.x % 100) * 64;
    const float* xb = x + b * (128 * 25600);

    {
        float scv = g[tid] * rsqrtf(vv[tid] + EPSBN);
        sc_s[tid] = scv;
        sh_s[tid] = bb[tid] - mm[tid] * scv;
    }

    const int k_in = tid & 31;
    const int prow = tid >> 5;
    int oh8[8], ow8[8];
    #pragma unroll
    for (int p = 0; p < 8; p++){
        int pix = pix0 + prow + p * 8;
        oh8[p] = pix / 80; ow8[p] = pix % 80;
    }

    const int wv   = tid >> 6;
    const int lane = tid & 63;
    const int lrow = lane & 15;
    const int quad = lane >> 4;

    float4v acc[4][4];
    #pragma unroll
    for (int i = 0; i < 4; i++)
        #pragma unroll
        for (int j = 0; j < 4; j++)
            acc[i][j] = (float4v){0.f, 0.f, 0.f, 0.f};

    for (int kc = 0; kc < 36; kc++){
        const int k0 = kc * 32;
        __syncthreads();

        #pragma unroll
        for (int p2 = 0; p2 < 4; p2++){
            int idx = p2 * 256 + tid;
            int oc  = idx >> 2;
            int kq  = idx & 3;
            *reinterpret_cast<uint4*>(&A_lds[oc * 40 + kq * 8]) =
                *reinterpret_cast<const uint4*>(wb + oc * 1152 + k0 + kq * 8);
        }

        {
            int kk  = k0 + k_in;
            int c   = kk / 9;
            int tap = kk - 9 * c;
            int kh  = tap / 3 - 1;
            int kw  = tap - 3 * (tap / 3) - 1;
            const float* xc = xb + c * 25600;
            #pragma unroll
            for (int p = 0; p < 8; p++){
                int ih = 2 * oh8[p] + kh;
                int iw = 2 * ow8[p] + kw;
                float v = 0.f;
                if ((ih | iw) >= 0) v = xc[ih * 160 + iw];
                B_lds[(prow + p * 8) * 40 + k_in] = (short)f2bf_bits(v);
            }
        }
        __syncthreads();

        short8 af[4], bfv[4];
        #pragma unroll
        for (int i = 0; i < 4; i++){
            int row = wv * 64 + i * 16 + lrow;
            af[i] = *reinterpret_cast<const short8*>(&A_lds[row * 40 + quad * 8]);
        }
        #pragma unroll
        for (int j = 0; j < 4; j++){
            bfv[j] = *reinterpret_cast<const short8*>(&B_lds[(j * 16 + lrow) * 40 + quad * 8]);
        }
        #pragma unroll
        for (int i = 0; i < 4; i++)
            #pragma unroll
            for (int j = 0; j < 4; j++)
                acc[i][j] = __builtin_amdgcn_mfma_f32_16x16x32_bf16(af[i], bfv[j], acc[i][j], 0, 0, 0);
    }

    #pragma unroll
    for (int i = 0; i < 4; i++){
        int oc0 = wv * 64 + i * 16 + quad * 4;
        float s0 = sc_s[oc0+0], h0 = sh_s[oc0+0];
        float s1 = sc_s[oc0+1], h1 = sh_s[oc0+1];
        float s2 = sc_s[oc0+2], h2 = sh_s[oc0+2];
        float s3 = sc_s[oc0+3], h3 = sh_s[oc0+3];
        #pragma unroll
        for (int j = 0; j < 4; j++){
            int pix = pix0 + j * 16 + lrow;
            unsigned short e0 = f2bf_bits(silu_(acc[i][j][0] * s0 + h0));
            unsigned short e1 = f2bf_bits(silu_(acc[i][j][1] * s1 + h1));
            unsigned short e2 = f2bf_bits(silu_(acc[i][j][2] * s2 + h2));
            unsigned short e3 = f2bf_bits(silu_(acc[i][j][3] * s3 + h3));
            ushort4 o; o.x = e0; o.y = e1; o.z = e2; o.w = e3;
            *reinterpret_cast<ushort4*>(hN + (b * 6400 + pix) * 256 + oc0) = o;
            // NCHW copy for the validated scalar k_off
            bf16* hc = hC + (b * 256 + oc0) * 6400 + pix;
            *reinterpret_cast<unsigned short*>(hc            ) = e0;
            *reinterpret_cast<unsigned short*>(hc + 6400     ) = e1;
            *reinterpret_cast<unsigned short*>(hc + 2 * 6400 ) = e2;
            *reinterpret_cast<unsigned short*>(hc + 3 * 6400 ) = e3;
        }
    }
}

// K1 (fallback): round-3 conv1, NCHW only.
__global__ __launch_bounds__(256) void k_conv1_nchw(
    const float* __restrict__ x, const bf16* __restrict__ wb,
    const float* __restrict__ g, const float* __restrict__ bb,
    const float* __restrict__ mm, const float* __restrict__ vv,
    bf16* __restrict__ h)
{
    __shared__ short A_lds[256 * 40];
    __shared__ short B_lds[64 * 40];
    __shared__ float sc_s[256], sh_s[256];

    const int tid  = threadIdx.x;
    const int b    = blockIdx.x / 100;
    const int pix0 = (blockIdx.x % 100) * 64;
    const float* xb = x + b * (128 * 25600);

    {
        float scv = g[tid] * rsqrtf(vv[tid] + EPSBN);
        sc_s[tid] = scv;
        sh_s[tid] = bb[tid] - mm[tid] * scv;
    }

    const int k_in = tid & 31;
    const int prow = tid >> 5;
    int oh8[8], ow8[8];
    #pragma unroll
    for (int p = 0; p < 8; p++){
        int pix = pix0 + prow + p * 8;
        oh8[p] = pix / 80; ow8[p] = pix % 80;
    }

    const int wv   = tid >> 6;
    const int lane = tid & 63;
    const int lrow = lane & 15;
    const int quad = lane >> 4;

    float4v acc[4][4];
    #pragma unroll
    for (int i = 0; i < 4; i++)
        #pragma unroll
        for (int j = 0; j < 4; j++)
            acc[i][j] = (float4v){0.f, 0.f, 0.f, 0.f};

    for (int kc = 0; kc < 36; kc++){
        const int k0 = kc * 32;
        __syncthreads();

        #pragma unroll
        for (int p2 = 0; p2 < 4; p2++){
            int idx = p2 * 256 + tid;
            int oc  = idx >> 2;
            int kq  = idx & 3;
            *reinterpret_cast<uint4*>(&A_lds[oc * 40 + kq * 8]) =
                *reinterpret_cast<const uint4*>(wb + oc * 1152 + k0 + kq * 8);
        }

        {
            int kk  = k0 + k_in;
            int c   = kk / 9;
            int tap = kk - 9 * c;
            int kh  = tap / 3 - 1;
            int kw  = tap - 3 * (tap / 3) - 1;
            const float* xc = xb + c * 25600;
            #pragma unroll
            for (int p = 0; p < 8; p++){
                int ih = 2 * oh8[p] + kh;
                int iw = 2 * ow8[p] + kw;
                float v = 0.f;
                if ((ih | iw) >= 0) v = xc[ih * 160 + iw];
                B_lds[(prow + p * 8) * 40 + k_in] = (short)f2bf_bits(v);
            }
        }
        __syncthreads();

        short8 af[4], bfv[4];
        #pragma unroll
        for (int i = 0; i < 4; i++){
            int row = wv * 64 + i * 16 + lrow;
            af[i] = *reinterpret_cast<const short8*>(&A_lds[row * 40 + quad * 8]);
        }
        #pragma unroll
        for (int j = 0; j < 4; j++){
            bfv[j] = *reinterpret_cast<const short8*>(&B_lds[(j * 16 + lrow) * 40 + quad * 8]);
        }
        #pragma unroll
        for (int i = 0; i < 4; i++)
            #pragma unroll
            for (int j = 0; j < 4; j++)
                acc[i][j] = __builtin_amdgcn_mfma_f32_16x16x32_bf16(af[i], bfv[j], acc[i][j], 0, 0, 0);
    }

    #pragma unroll
    for (int i = 0; i < 4; i++){
        #pragma unroll
        for (int r = 0; r < 4; r++){
            int oc = wv * 64 + i * 16 + quad * 4 + r;
            float scv = sc_s[oc], shv = sh_s[oc];
            #pragma unroll
            for (int j = 0; j < 4; j++){
                int pix = pix0 + j * 16 + lrow;
                float y = acc[i][j][r] * scv + shv;
                h[(b * 256 + oc) * 6400 + pix] = __float2bfloat16(silu_(y));
            }
        }
    }
}

// ---------------------------------------------------------------------------
// K2: VALIDATED round-2/3 scalar offset conv (reads NCHW h).
__global__ __launch_bounds__(256) void k_off_s(
    const bf16* __restrict__ h, const float* __restrict__ w,
    const float* __restrict__ bias, float* __restrict__ off)
{
    __shared__ float ws_[256 * 9];
    const int tid = threadIdx.x;
    const int blk = blockIdx.x;                    // 3600 = 8*18*25
    const int boc = blk / 25;
    const int oc  = boc % 18;
    const int b   = boc / 18;
    const int pix = (blk % 25) * 256 + tid;

    for (int i = tid; i < 2304; i += 256) ws_[i] = w[oc * 2304 + i];
    __syncthreads();

    const int oh = pix / 80, ow = pix % 80;
    int ofs[9]; float msk[9];
    #pragma unroll
    for (int tap = 0; tap < 9; tap++){
        int kh = tap / 3, kw = tap % 3;
        int ih = oh + kh - 1, iw = ow + kw - 1;
        bool val = (ih >= 0) && (ih < 80) && (iw >= 0) && (iw < 80);
        int ihc = min(max(ih, 0), 79), iwc = min(max(iw, 0), 79);
        ofs[tap] = ihc * 80 + iwc;
        msk[tap] = val ? 1.f : 0.f;
    }

    const bf16* hb = h + b * (256 * 6400);
    float acc = bias[oc];
    for (int c = 0; c < 256; c++){
        const bf16*  hc = hb + c * 6400;
        const float* wc = &ws_[c * 9];
        #pragma unroll
        for (int tap = 0; tap < 9; tap++){
            acc += bf2f(hc[ofs[tap]]) * msk[tap] * wc[tap];
        }
    }
    off[boc * 6400 + pix] = acc;
}

// ---------------------------------------------------------------------------
// K3 (primary, SUSPECT): round-4 deform conv MFMA on NHWC h, verbatim.
__global__ __launch_bounds__(256) void k_dconv_nhwc(
    const bf16* __restrict__ hN, const float* __restrict__ off,
    const bf16* __restrict__ wb2,
    const float* __restrict__ g, const float* __restrict__ bb,
    const float* __restrict__ mm, const float* __restrict__ vv,
    float* __restrict__ out)
{
    __shared__ short   A_lds[256 * 40];
    __shared__ short   B_lds[64 * 40];
    __shared__ ushort4 sidxu[576];
    __shared__ ushort4 swtu [576];
    __shared__ float   sc_s[256], sh_s[256];

    const int tid  = threadIdx.x;
    const int b    = blockIdx.x / 100;
    const int pix0 = (blockIdx.x % 100) * 64;
    const bf16* hb = hN + b * (6400 * 256);

    {
        float scv = g[tid] * rsqrtf(vv[tid] + EPSBN);
        sc_s[tid] = scv;
        sh_s[tid] = bb[tid] - mm[tid] * scv;
    }

    for (int e = tid; e < 576; e += 256){
        int t = e & 63, k = e >> 6;
        int pix = pix0 + t;
        int oh = pix / 80, ow = pix % 80;
        int kh = k / 3, kw = k % 3;
        float oy = off[(b * 18 + 2 * k    ) * 6400 + pix];
        float ox = off[(b * 18 + 2 * k + 1) * 6400 + pix];
        float py = (float)(oh + kh - 1) + oy;
        float px = (float)(ow + kw - 1) + ox;
        float y0f = floorf(py), x0f = floorf(px);
        float wy1 = py - y0f,  wx1 = px - x0f;
        int y0 = (int)y0f, x0 = (int)x0f;
        unsigned short ii[4], ww[4];
        #pragma unroll
        for (int cy = 0; cy < 2; cy++){
            int   yy = y0 + cy;
            float wy = cy ? wy1 : 1.f - wy1;
            bool  vy = (yy >= 0) && (yy < 80);
            int   yc = min(max(yy, 0), 79);
            #pragma unroll
            for (int cx = 0; cx < 2; cx++){
                int   xx = x0 + cx;
                float wx = cx ? wx1 : 1.f - wx1;
                bool  vx = (xx >= 0) && (xx < 80);
                int   xc = min(max(xx, 0), 79);
                int ci = cy * 2 + cx;
                ii[ci] = (unsigned short)(yc * 80 + xc);
                ww[ci] = f2bf_bits((vy && vx) ? wy * wx : 0.f);
            }
        }
        ushort4 iv; iv.x = ii[0]; iv.y = ii[1]; iv.z = ii[2]; iv.w = ii[3];
        ushort4 wv_; wv_.x = ww[0]; wv_.y = ww[1]; wv_.z = ww[2]; wv_.w = ww[3];
        sidxu[e] = iv;
        swtu [e] = wv_;
    }
    __syncthreads();

    const int t4   = tid >> 2;
    const int cq   = tid & 3;
    const int wv   = tid >> 6;
    const int lane = tid & 63;
    const int lrow = lane & 15;
    const int quad = lane >> 4;

    float4v acc[4][4];
    #pragma unroll
    for (int i = 0; i < 4; i++)
        #pragma unroll
        for (int j = 0; j < 4; j++)
            acc[i][j] = (float4v){0.f, 0.f, 0.f, 0.f};

    for (int tap = 0; tap < 9; tap++){
        const int e = tap * 64 + t4;
        ushort4 ipk = sidxu[e];
        ushort4 wpk = swtu[e];
        const float w0 = bits2f(wpk.x), w1 = bits2f(wpk.y),
                    w2 = bits2f(wpk.z), w3 = bits2f(wpk.w);
        const int i0 = (int)ipk.x * 256, i1 = (int)ipk.y * 256,
                  i2 = (int)ipk.z * 256, i3 = (int)ipk.w * 256;

        for (int sub = 0; sub < 8; sub++){
            const int kc = tap * 8 + sub;
            __syncthreads();

            #pragma unroll
            for (int p2 = 0; p2 < 4; p2++){
                int idx = p2 * 256 + tid;
                int oc  = idx >> 2;
                int kq  = idx & 3;
                *reinterpret_cast<uint4*>(&A_lds[oc * 40 + kq * 8]) =
                    *reinterpret_cast<const uint4*>(wb2 + oc * 2304 + kc * 32 + kq * 8);
            }

            {
                const int cb = sub * 32;
                #pragma unroll
                for (int p = 0; p < 2; p++){
                    int kci0 = cq * 4 + p * 16;
                    int co   = cb + kci0;
                    ushort4 ca = *reinterpret_cast<const ushort4*>(hb + i0 + co);
                    ushort4 cbv= *reinterpret_cast<const ushort4*>(hb + i1 + co);
                    ushort4 cc = *reinterpret_cast<const ushort4*>(hb + i2 + co);
                    ushort4 cd = *reinterpret_cast<const ushort4*>(hb + i3 + co);
                    ushort4 o;
                    o.x = f2bf_bits(w0*bits2f(ca.x) + w1*bits2f(cbv.x) + w2*bits2f(cc.x) + w3*bits2f(cd.x));
                    o.y = f2bf_bits(w0*bits2f(ca.y) + w1*bits2f(cbv.y) + w2*bits2f(cc.y) + w3*bits2f(cd.y));
                    o.z = f2bf_bits(w0*bits2f(ca.z) + w1*bits2f(cbv.z) + w2*bits2f(cc.z) + w3*bits2f(cd.z));
                    o.w = f2bf_bits(w0*bits2f(ca.w) + w1*bits2f(cbv.w) + w2*bits2f(cc.w) + w3*bits2f(cd.w));
                    *reinterpret_cast<ushort4*>(&B_lds[t4 * 40 + kci0]) = o;
                }
            }
            __syncthreads();

            short8 af[4], bfv[4];
            #pragma unroll
            for (int i = 0; i < 4; i++){
                int row = wv * 64 + i * 16 + lrow;
                af[i] = *reinterpret_cast<const short8*>(&A_lds[row * 40 + quad * 8]);
            }
            #pragma unroll
            for (int j = 0; j < 4; j++){
                bfv[j] = *reinterpret_cast<const short8*>(&B_lds[(j * 16 + lrow) * 40 + quad * 8]);
            }
            #pragma unroll
            for (int i = 0; i < 4; i++)
                #pragma unroll
                for (int j = 0; j < 4; j++)
                    acc[i][j] = __builtin_amdgcn_mfma_f32_16x16x32_bf16(af[i], bfv[j], acc[i][j], 0, 0, 0);
        }
    }

    #pragma unroll
    for (int i = 0; i < 4; i++){
        #pragma unroll
        for (int r = 0; r < 4; r++){
            int oc = wv * 64 + i * 16 + quad * 4 + r;
            float scv = sc_s[oc], shv = sh_s[oc];
            #pragma unroll
            for (int j = 0; j < 4; j++){
                int pix = pix0 + j * 16 + lrow;
                out[(b * 256 + oc) * 6400 + pix] = silu_(acc[i][j][r] * scv + shv);
            }
        }
    }
}

// ---------------------------------------------------------------------------
// K3 (fallback, VALIDATED): round-3 deform conv MFMA on NCHW h, verbatim.
__global__ __launch_bounds__(256) void k_dconv_nchw(
    const bf16* __restrict__ h, const float* __restrict__ off,
    const bf16* __restrict__ wb2,
    const float* __restrict__ g, const float* __restrict__ bb,
    const float* __restrict__ mm, const float* __restrict__ vv,
    float* __restrict__ out)
{
    __shared__ short  A_lds[256 * 40];
    __shared__ short  B_lds[64 * 40];
    __shared__ int4   sidx4[576];
    __shared__ float4 swt4 [576];
    __shared__ float  sc_s[256], sh_s[256];

    const int tid  = threadIdx.x;
    const int b    = blockIdx.x / 100;
    const int pix0 = (blockIdx.x % 100) * 64;
    const bf16* hb = h + b * (256 * 6400);

    {
        float scv = g[tid] * rsqrtf(vv[tid] + EPSBN);
        sc_s[tid] = scv;
        sh_s[tid] = bb[tid] - mm[tid] * scv;
    }

    for (int e = tid; e < 576; e += 256){
        int t = e & 63, k = e >> 6;
        int pix = pix0 + t;
        int oh = pix / 80, ow = pix % 80;
        int kh = k / 3, kw = k % 3;
        float oy = off[(b * 18 + 2 * k    ) * 6400 + pix];
        float ox = off[(b * 18 + 2 * k + 1) * 6400 + pix];
        float py = (float)(oh + kh - 1) + oy;
        float px = (float)(ow + kw - 1) + ox;
        float y0f = floorf(py), x0f = floorf(px);
        float wy1 = py - y0f,  wx1 = px - x0f;
        int y0 = (int)y0f, x0 = (int)x0f;
        int   ii[4]; float ww[4];
        #pragma unroll
        for (int cy = 0; cy < 2; cy++){
            int   yy = y0 + cy;
            float wy = cy ? wy1 : 1.f - wy1;
            bool  vy = (yy >= 0) && (yy < 80);
            int   yc = min(max(yy, 0), 79);
            #pragma unroll
            for (int cx = 0; cx < 2; cx++){
                int   xx = x0 + cx;
                float wx = cx ? wx1 : 1.f - wx1;
                bool  vx = (xx >= 0) && (xx < 80);
                int   xc = min(max(xx, 0), 79);
                int ci = cy * 2 + cx;
                ii[ci] = yc * 80 + xc;
                ww[ci] = (vy && vx) ? wy * wx : 0.f;
            }
        }
        sidx4[e] = make_int4(ii[0], ii[1], ii[2], ii[3]);
        swt4 [e] = make_float4(ww[0], ww[1], ww[2], ww[3]);
    }

    const int k_in = tid & 31;
    const int prow = tid >> 5;
    const int wv   = tid >> 6;
    const int lane = tid & 63;
    const int lrow = lane & 15;
    const int quad = lane >> 4;

    float4v acc[4][4];
    #pragma unroll
    for (int i = 0; i < 4; i++)
        #pragma unroll
        for (int j = 0; j < 4; j++)
            acc[i][j] = (float4v){0.f, 0.f, 0.f, 0.f};

    for (int kc = 0; kc < 72; kc++){
        __syncthreads();

        #pragma unroll
        for (int p2 = 0; p2 < 4; p2++){
            int idx = p2 * 256 + tid;
            int oc  = idx >> 2;
            int kq  = idx & 3;
            *reinterpret_cast<uint4*>(&A_lds[oc * 40 + kq * 8]) =
                *reinterpret_cast<const uint4*>(wb2 + oc * 2304 + kc * 32 + kq * 8);
        }

        {
            const int tap = kc >> 3;
            const int c   = ((kc & 7) << 5) + k_in;
            const bf16* hc = hb + c * 6400;
            #pragma unroll
            for (int p = 0; p < 8; p++){
                int t = prow + p * 8;
                int e = tap * 64 + t;
                int4   ip = sidx4[e];
                float4 wp = swt4[e];
                float s = wp.x * bf2f(hc[ip.x]) + wp.y * bf2f(hc[ip.y])
                        + wp.z * bf2f(hc[ip.z]) + wp.w * bf2f(hc[ip.w]);
                B_lds[t * 40 + k_in] = (short)f2bf_bits(s);
            }
        }
        __syncthreads();

        short8 af[4], bfv[4];
        #pragma unroll
        for (int i = 0; i < 4; i++){
            int row = wv * 64 + i * 16 + lrow;
            af[i] = *reinterpret_cast<const short8*>(&A_lds[row * 40 + quad * 8]);
        }
        #pragma unroll
        for (int j = 0; j < 4; j++){
            bfv[j] = *reinterpret_cast<const short8*>(&B_lds[(j * 16 + lrow) * 40 + quad * 8]);
        }
        #pragma unroll
        for (int i = 0; i < 4; i++)
            #pragma unroll
            for (int j = 0; j < 4; j++)
                acc[i][j] = __builtin_amdgcn_mfma_f32_16x16x32_bf16(af[i], bfv[j], acc[i][j], 0, 0, 0);
    }

    #pragma unroll
    for (int i = 0; i < 4; i++){
        #pragma unroll
        for (int r = 0; r < 4; r++){
            int oc = wv * 64 + i * 16 + quad * 4 + r;
            float scv = sc_s[oc], shv = sh_s[oc];
            #pragma unroll
            for (int j = 0; j < 4; j++){
                int pix = pix0 + j * 16 + lrow;
                out[(b * 256 + oc) * 6400 + pix] = silu_(acc[i][j][r] * scv + shv);
            }
        }
    }
}

// ---------------------------------------------------------------------------
extern "C" void kernel_launch(void* const* d_in, const int* in_sizes, int n_in,
                              void* d_out, int out_size, void* d_ws, size_t ws_size,
                              hipStream_t stream)
{
    (void)in_sizes; (void)n_in; (void)out_size;

    const float* x  = (const float*)d_in[0];
    const float* w1 = (const float*)d_in[1];
    const float* g1 = (const float*)d_in[2];
    const float* b1 = (const float*)d_in[3];
    const float* m1 = (const float*)d_in[4];
    const float* v1 = (const float*)d_in[5];
    const float* wo = (const float*)d_in[6];
    const float* bo = (const float*)d_in[7];
    const float* wd = (const float*)d_in[8];
    const float* g2 = (const float*)d_in[9];
    const float* b2 = (const float*)d_in[10];
    const float* m2 = (const float*)d_in[11];
    const float* v2 = (const float*)d_in[12];
    float* outp = (float*)d_out;

    char* wsb = (char*)d_ws;
    const size_t need_primary = 57884672;   // hN + hC + off + wb2 + wb

    if (ws_size >= need_primary){
        bf16*  hNb  = (bf16*) wsb;                      // 26,214,400 B
        bf16*  hCb  = (bf16*) (wsb + 26214400);         // 26,214,400 B
        float* obuf = (float*)(wsb + 52428800);         //  3,686,400 B
        bf16*  wb2b = (bf16*) (wsb + 56115200);         //  1,179,648 B
        bf16*  wbb  = (bf16*) (wsb + 57294848);         //    589,824 B

        hipLaunchKernelGGL(k_wdprep,    dim3(2304), dim3(256), 0, stream, wd, wb2b);
        hipLaunchKernelGGL(k_wprep,     dim3(1152), dim3(256), 0, stream, w1, wbb);
        hipLaunchKernelGGL(k_conv1_dual,dim3(800),  dim3(256), 0, stream, x, wbb, g1, b1, m1, v1, hNb, hCb);
        hipLaunchKernelGGL(k_off_s,     dim3(3600), dim3(256), 0, stream, hCb, wo, bo, obuf);
        hipLaunchKernelGGL(k_dconv_nhwc,dim3(800),  dim3(256), 0, stream, hNb, obuf, wb2b, g2, b2, m2, v2, outp);
    } else {
        // round-3 validated configuration
        bf16*  hCb  = (bf16*) wsb;                      // 26,214,400 B
        float* obuf = (float*)(wsb + 26214400);         //  3,686,400 B
        bf16*  wb2b = (bf16*) (wsb + 29900800);         //  1,179,648 B
        bf16*  wbb  = (bf16*) (wsb + 31080448);         //    589,824 B

        hipLaunchKernelGGL(k_wdprep,    dim3(2304), dim3(256), 0, stream, wd, wb2b);
        hipLaunchKernelGGL(k_wprep,     dim3(1152), dim3(256), 0, stream, w1, wbb);
        hipLaunchKernelGGL(k_conv1_nchw,dim3(800),  dim3(256), 0, stream, x, wbb, g1, b1, m1, v1, hCb);
        hipLaunchKernelGGL(k_off_s,     dim3(3600), dim3(256), 0, stream, hCb, wo, bo, obuf);
        hipLaunchKernelGGL(k_dconv_nchw,dim3(800),  dim3(256), 0, stream, hCb, obuf, wb2b, g2, b2, m2, v2, outp);
    }
}

// Round 7
// 730.856 us; speedup vs baseline: 2.4343x; 1.1917x over previous
//
#include <hip/hip_runtime.h>
#include <hip/hip_bf16.h>

// DCNConv pipeline, MI355X round 6.
// Validated (r5 bisect): NHWC MFMA k_dconv + NHWC conv1 epilogue. The r4 bug
// was the MFMA k_off; replaced here by a vectorized VALU k_off on NHWC h with
// sgpr (s_load) weights: lane = pixel, wave = 64-channel slice, weights
// pre-transposed to [tap][c][18] so per 4-ch step = 72 v_fmac + 1 ushort4 gather.
//
// Shapes: x[8,128,160,160] -> conv3x3 s2 p1 + BN + SiLU -> h[8,256,80,80]
//         h -> conv3x3 s1 p1 (+bias) -> offset[8,18,80,80]
//         deform_conv3x3(h, offset, dconv_w) -> y[8,256,80,80] -> BN+SiLU (fp32)
//
// Workspace (31.84 MB):
//   [0)          hN  bf16 [8][6400pix][256c] = 26,214,400 B
//   [26,214,400) off fp32 [8][18][6400]      =  3,686,400 B
//   [29,900,800) wb2 bf16 [256][2304]        =  1,179,648 B (dconv w, tap-major)
//   [31,080,448) wb  bf16 [256][1152]        =    589,824 B (conv1 w)
//   [31,670,272) wToff fp32 [9][256][18]     =    165,888 B (off w, transposed)

typedef __hip_bfloat16 bf16;
typedef __attribute__((ext_vector_type(8))) short short8;
typedef __attribute__((ext_vector_type(4))) float float4v;

#define EPSBN 1e-5f

__device__ __forceinline__ float bf2f(bf16 x){ return __bfloat162float(x); }
__device__ __forceinline__ float bits2f(unsigned short u){ return __uint_as_float(((unsigned)u) << 16); }
__device__ __forceinline__ float silu_(float x){ return x / (1.f + __expf(-x)); }
__device__ __forceinline__ unsigned short f2bf_bits(float f){
    union { float f; unsigned u; } uf; uf.f = f;
    unsigned r = uf.u + 0x7fff + ((uf.u >> 16) & 1);   // RNE (finite inputs)
    return (unsigned short)(r >> 16);
}

// ---------------------------------------------------------------------------
// K0a: dconv_w [256oc][256c][9tap] fp32 -> wb2 bf16 [256oc][2304], kk = tap*256+c.
__global__ __launch_bounds__(256) void k_wdprep(const float* __restrict__ w, bf16* __restrict__ wb2)
{
    int idx = blockIdx.x * 256 + threadIdx.x;
    if (idx >= 256 * 2304) return;
    int oc  = idx / 2304;
    int r   = idx - oc * 2304;
    int tap = r >> 8;
    int c   = r & 255;
    wb2[idx] = __float2bfloat16(w[(oc * 256 + c) * 9 + tap]);
}

// K0b: conv1 weights fp32 -> bf16.
__global__ __launch_bounds__(256) void k_wprep(const float* __restrict__ w, bf16* __restrict__ wb)
{
    int idx = blockIdx.x * 256 + threadIdx.x;
    if (idx >= 256 * 1152) return;
    wb[idx] = __float2bfloat16(w[idx]);
}

// K0c: off_w [18oc][256c][9tap] fp32 -> wToff fp32 [(tap*256+c)*18 + oc].
__global__ __launch_bounds__(256) void k_woprep2(const float* __restrict__ w, float* __restrict__ wT)
{
    int idx = blockIdx.x * 256 + threadIdx.x;      // 41,472 total
    if (idx >= 9 * 256 * 18) return;
    int oc  = idx % 18;
    int r   = idx / 18;
    int c   = r & 255;
    int tap = r >> 8;
    wT[idx] = w[(oc * 256 + c) * 9 + tap];
}

// ---------------------------------------------------------------------------
// K1: conv1 (3x3 s2 p1) + BN1 + SiLU via MFMA implicit GEMM, NHWC output
// (validated in rounds 4/5 via the dual-store variant).
__global__ __launch_bounds__(256) void k_conv1(
    const float* __restrict__ x, const bf16* __restrict__ wb,
    const float* __restrict__ g, const float* __restrict__ bb,
    const float* __restrict__ mm, const float* __restrict__ vv,
    bf16* __restrict__ hN)
{
    __shared__ short A_lds[256 * 40];
    __shared__ short B_lds[64 * 40];
    __shared__ float sc_s[256], sh_s[256];

    const int tid  = threadIdx.x;
    const int b    = blockIdx.x / 100;
    const int pix0 = (blockIdx.x % 100) * 64;
    const float* xb = x + b * (128 * 25600);

    {
        float scv = g[tid] * rsqrtf(vv[tid] + EPSBN);
        sc_s[tid] = scv;
        sh_s[tid] = bb[tid] - mm[tid] * scv;
    }

    const int k_in = tid & 31;
    const int prow = tid >> 5;
    int oh8[8], ow8[8];
    #pragma unroll
    for (int p = 0; p < 8; p++){
        int pix = pix0 + prow + p * 8;
        oh8[p] = pix / 80; ow8[p] = pix % 80;
    }

    const int wv   = tid >> 6;
    const int lane = tid & 63;
    const int lrow = lane & 15;
    const int quad = lane >> 4;

    float4v acc[4][4];
    #pragma unroll
    for (int i = 0; i < 4; i++)
        #pragma unroll
        for (int j = 0; j < 4; j++)
            acc[i][j] = (float4v){0.f, 0.f, 0.f, 0.f};

    for (int kc = 0; kc < 36; kc++){
        const int k0 = kc * 32;
        __syncthreads();

        #pragma unroll
        for (int p2 = 0; p2 < 4; p2++){
            int idx = p2 * 256 + tid;
            int oc  = idx >> 2;
            int kq  = idx & 3;
            *reinterpret_cast<uint4*>(&A_lds[oc * 40 + kq * 8]) =
                *reinterpret_cast<const uint4*>(wb + oc * 1152 + k0 + kq * 8);
        }

        {
            int kk  = k0 + k_in;
            int c   = kk / 9;
            int tap = kk - 9 * c;
            int kh  = tap / 3 - 1;
            int kw  = tap - 3 * (tap / 3) - 1;
            const float* xc = xb + c * 25600;
            #pragma unroll
            for (int p = 0; p < 8; p++){
                int ih = 2 * oh8[p] + kh;
                int iw = 2 * ow8[p] + kw;
                float v = 0.f;
                if ((ih | iw) >= 0) v = xc[ih * 160 + iw];
                B_lds[(prow + p * 8) * 40 + k_in] = (short)f2bf_bits(v);
            }
        }
        __syncthreads();

        short8 af[4], bfv[4];
        #pragma unroll
        for (int i = 0; i < 4; i++){
            int row = wv * 64 + i * 16 + lrow;
            af[i] = *reinterpret_cast<const short8*>(&A_lds[row * 40 + quad * 8]);
        }
        #pragma unroll
        for (int j = 0; j < 4; j++){
            bfv[j] = *reinterpret_cast<const short8*>(&B_lds[(j * 16 + lrow) * 40 + quad * 8]);
        }
        #pragma unroll
        for (int i = 0; i < 4; i++)
            #pragma unroll
            for (int j = 0; j < 4; j++)
                acc[i][j] = __builtin_amdgcn_mfma_f32_16x16x32_bf16(af[i], bfv[j], acc[i][j], 0, 0, 0);
    }

    #pragma unroll
    for (int i = 0; i < 4; i++){
        int oc0 = wv * 64 + i * 16 + quad * 4;
        float s0 = sc_s[oc0+0], h0 = sh_s[oc0+0];
        float s1 = sc_s[oc0+1], h1 = sh_s[oc0+1];
        float s2 = sc_s[oc0+2], h2 = sh_s[oc0+2];
        float s3 = sc_s[oc0+3], h3 = sh_s[oc0+3];
        #pragma unroll
        for (int j = 0; j < 4; j++){
            int pix = pix0 + j * 16 + lrow;
            ushort4 o;
            o.x = f2bf_bits(silu_(acc[i][j][0] * s0 + h0));
            o.y = f2bf_bits(silu_(acc[i][j][1] * s1 + h1));
            o.z = f2bf_bits(silu_(acc[i][j][2] * s2 + h2));
            o.w = f2bf_bits(silu_(acc[i][j][3] * s3 + h3));
            *reinterpret_cast<ushort4*>(hN + (b * 6400 + pix) * 256 + oc0) = o;
        }
    }
}

// ---------------------------------------------------------------------------
// K2: offset conv via vectorized VALU on NHWC h.
// Block = 64 pixels; lane = pixel; wave wv owns channels [wv*64, wv*64+64)
// (readfirstlane -> provably wave-uniform -> weights come in via s_load).
// Inner step: 1 ushort4 h-gather (4 ch) + 72 v_fmac against 72 sgpr weights.
// Cross-wave reduce of acc[18] through LDS.
__global__ __launch_bounds__(256) void k_off_v(
    const bf16* __restrict__ hN, const float* __restrict__ wT,
    const float* __restrict__ bias, float* __restrict__ off)
{
    __shared__ float red[4 * 18 * 64];             // 18,432 B

    const int tid   = threadIdx.x;
    const int b     = blockIdx.x / 100;            // 800 blocks
    const int pix0  = (blockIdx.x % 100) * 64;
    const int lane  = tid & 63;
    const int wv    = tid >> 6;
    const int cbase = __builtin_amdgcn_readfirstlane(wv << 6);  // wave-uniform sgpr

    const int pix = pix0 + lane;
    const int oh  = pix / 80, ow = pix % 80;

    float acc[18];
    #pragma unroll
    for (int o = 0; o < 18; o++) acc[o] = 0.f;

    for (int tap = 0; tap < 9; tap++){
        int ih = oh + tap / 3 - 1, iw = ow + tap % 3 - 1;
        bool val = ((unsigned)ih < 80u) && ((unsigned)iw < 80u);
        int  sp  = min(max(ih, 0), 79) * 80 + min(max(iw, 0), 79);
        float m  = val ? 1.f : 0.f;
        const bf16*  hp = hN + (size_t)(b * 6400 + sp) * 256 + cbase;
        const float* wp = wT + (tap * 256 + cbase) * 18;
        for (int cs = 0; cs < 64; cs += 4){
            ushort4 hv = *reinterpret_cast<const ushort4*>(hp + cs);
            float h0 = bits2f(hv.x) * m, h1 = bits2f(hv.y) * m,
                  h2 = bits2f(hv.z) * m, h3 = bits2f(hv.w) * m;
            const float* w0 = wp + cs * 18;        // wave-uniform -> s_load
            #pragma unroll
            for (int o = 0; o < 18; o++){
                acc[o] += h0 * w0[o] + h1 * w0[18 + o] + h2 * w0[36 + o] + h3 * w0[54 + o];
            }
        }
    }

    #pragma unroll
    for (int o = 0; o < 18; o++)
        red[(wv * 18 + o) * 64 + lane] = acc[o];
    __syncthreads();

    for (int i = tid; i < 18 * 64; i += 256){
        int o = i >> 6, p = i & 63;
        float s = red[(0 * 18 + o) * 64 + p] + red[(1 * 18 + o) * 64 + p]
                + red[(2 * 18 + o) * 64 + p] + red[(3 * 18 + o) * 64 + p] + bias[o];
        off[(b * 18 + o) * 6400 + pix0 + p] = s;
    }
}

// ---------------------------------------------------------------------------
// K3: deform conv MFMA on NHWC h (validated round 5, verbatim).
__global__ __launch_bounds__(256) void k_dconv_nhwc(
    const bf16* __restrict__ hN, const float* __restrict__ off,
    const bf16* __restrict__ wb2,
    const float* __restrict__ g, const float* __restrict__ bb,
    const float* __restrict__ mm, const float* __restrict__ vv,
    float* __restrict__ out)
{
    __shared__ short   A_lds[256 * 40];
    __shared__ short   B_lds[64 * 40];
    __shared__ ushort4 sidxu[576];
    __shared__ ushort4 swtu [576];
    __shared__ float   sc_s[256], sh_s[256];

    const int tid  = threadIdx.x;
    const int b    = blockIdx.x / 100;
    const int pix0 = (blockIdx.x % 100) * 64;
    const bf16* hb = hN + b * (6400 * 256);

    {
        float scv = g[tid] * rsqrtf(vv[tid] + EPSBN);
        sc_s[tid] = scv;
        sh_s[tid] = bb[tid] - mm[tid] * scv;
    }

    for (int e = tid; e < 576; e += 256){
        int t = e & 63, k = e >> 6;
        int pix = pix0 + t;
        int oh = pix / 80, ow = pix % 80;
        int kh = k / 3, kw = k % 3;
        float oy = off[(b * 18 + 2 * k    ) * 6400 + pix];
        float ox = off[(b * 18 + 2 * k + 1) * 6400 + pix];
        float py = (float)(oh + kh - 1) + oy;
        float px = (float)(ow + kw - 1) + ox;
        float y0f = floorf(py), x0f = floorf(px);
        float wy1 = py - y0f,  wx1 = px - x0f;
        int y0 = (int)y0f, x0 = (int)x0f;
        unsigned short ii[4], ww[4];
        #pragma unroll
        for (int cy = 0; cy < 2; cy++){
            int   yy = y0 + cy;
            float wy = cy ? wy1 : 1.f - wy1;
            bool  vy = (yy >= 0) && (yy < 80);
            int   yc = min(max(yy, 0), 79);
            #pragma unroll
            for (int cx = 0; cx < 2; cx++){
                int   xx = x0 + cx;
                float wx = cx ? wx1 : 1.f - wx1;
                bool  vx = (xx >= 0) && (xx < 80);
                int   xc = min(max(xx, 0), 79);
                int ci = cy * 2 + cx;
                ii[ci] = (unsigned short)(yc * 80 + xc);
                ww[ci] = f2bf_bits((vy && vx) ? wy * wx : 0.f);
            }
        }
        ushort4 iv; iv.x = ii[0]; iv.y = ii[1]; iv.z = ii[2]; iv.w = ii[3];
        ushort4 wv_; wv_.x = ww[0]; wv_.y = ww[1]; wv_.z = ww[2]; wv_.w = ww[3];
        sidxu[e] = iv;
        swtu [e] = wv_;
    }
    __syncthreads();

    const int t4   = tid >> 2;
    const int cq   = tid & 3;
    const int wv   = tid >> 6;
    const int lane = tid & 63;
    const int lrow = lane & 15;
    const int quad = lane >> 4;

    float4v acc[4][4];
    #pragma unroll
    for (int i = 0; i < 4; i++)
        #pragma unroll
        for (int j = 0; j < 4; j++)
            acc[i][j] = (float4v){0.f, 0.f, 0.f, 0.f};

    for (int tap = 0; tap < 9; tap++){
        const int e = tap * 64 + t4;
        ushort4 ipk = sidxu[e];
        ushort4 wpk = swtu[e];
        const float w0 = bits2f(wpk.x), w1 = bits2f(wpk.y),
                    w2 = bits2f(wpk.z), w3 = bits2f(wpk.w);
        const int i0 = (int)ipk.x * 256, i1 = (int)ipk.y * 256,
                  i2 = (int)ipk.z * 256, i3 = (int)ipk.w * 256;

        for (int sub = 0; sub < 8; sub++){
            const int kc = tap * 8 + sub;
            __syncthreads();

            #pragma unroll
            for (int p2 = 0; p2 < 4; p2++){
                int idx = p2 * 256 + tid;
                int oc  = idx >> 2;
                int kq  = idx & 3;
                *reinterpret_cast<uint4*>(&A_lds[oc * 40 + kq * 8]) =
                    *reinterpret_cast<const uint4*>(wb2 + oc * 2304 + kc * 32 + kq * 8);
            }

            {
                const int cb = sub * 32;
                #pragma unroll
                for (int p = 0; p < 2; p++){
                    int kci0 = cq * 4 + p * 16;
                    int co   = cb + kci0;
                    ushort4 ca = *reinterpret_cast<const ushort4*>(hb + i0 + co);
                    ushort4 cbv= *reinterpret_cast<const ushort4*>(hb + i1 + co);
                    ushort4 cc = *reinterpret_cast<const ushort4*>(hb + i2 + co);
                    ushort4 cd = *reinterpret_cast<const ushort4*>(hb + i3 + co);
                    ushort4 o;
                    o.x = f2bf_bits(w0*bits2f(ca.x) + w1*bits2f(cbv.x) + w2*bits2f(cc.x) + w3*bits2f(cd.x));
                    o.y = f2bf_bits(w0*bits2f(ca.y) + w1*bits2f(cbv.y) + w2*bits2f(cc.y) + w3*bits2f(cd.y));
                    o.z = f2bf_bits(w0*bits2f(ca.z) + w1*bits2f(cbv.z) + w2*bits2f(cc.z) + w3*bits2f(cd.z));
                    o.w = f2bf_bits(w0*bits2f(ca.w) + w1*bits2f(cbv.w) + w2*bits2f(cc.w) + w3*bits2f(cd.w));
                    *reinterpret_cast<ushort4*>(&B_lds[t4 * 40 + kci0]) = o;
                }
            }
            __syncthreads();

            short8 af[4], bfv[4];
            #pragma unroll
            for (int i = 0; i < 4; i++){
                int row = wv * 64 + i * 16 + lrow;
                af[i] = *reinterpret_cast<const short8*>(&A_lds[row * 40 + quad * 8]);
            }
            #pragma unroll
            for (int j = 0; j < 4; j++){
                bfv[j] = *reinterpret_cast<const short8*>(&B_lds[(j * 16 + lrow) * 40 + quad * 8]);
            }
            #pragma unroll
            for (int i = 0; i < 4; i++)
                #pragma unroll
                for (int j = 0; j < 4; j++)
                    acc[i][j] = __builtin_amdgcn_mfma_f32_16x16x32_bf16(af[i], bfv[j], acc[i][j], 0, 0, 0);
        }
    }

    #pragma unroll
    for (int i = 0; i < 4; i++){
        #pragma unroll
        for (int r = 0; r < 4; r++){
            int oc = wv * 64 + i * 16 + quad * 4 + r;
            float scv = sc_s[oc], shv = sh_s[oc];
            #pragma unroll
            for (int j = 0; j < 4; j++){
                int pix = pix0 + j * 16 + lrow;
                out[(b * 256 + oc) * 6400 + pix] = silu_(acc[i][j][r] * scv + shv);
            }
        }
    }
}

// ---------------------------------------------------------------------------
extern "C" void kernel_launch(void* const* d_in, const int* in_sizes, int n_in,
                              void* d_out, int out_size, void* d_ws, size_t ws_size,
                              hipStream_t stream)
{
    (void)in_sizes; (void)n_in; (void)out_size; (void)ws_size;

    const float* x  = (const float*)d_in[0];
    const float* w1 = (const float*)d_in[1];
    const float* g1 = (const float*)d_in[2];
    const float* b1 = (const float*)d_in[3];
    const float* m1 = (const float*)d_in[4];
    const float* v1 = (const float*)d_in[5];
    const float* wo = (const float*)d_in[6];
    const float* bo = (const float*)d_in[7];
    const float* wd = (const float*)d_in[8];
    const float* g2 = (const float*)d_in[9];
    const float* b2 = (const float*)d_in[10];
    const float* m2 = (const float*)d_in[11];
    const float* v2 = (const float*)d_in[12];
    float* outp = (float*)d_out;

    char*  wsb  = (char*)d_ws;
    bf16*  hNb  = (bf16*) wsb;                      // 26,214,400 B
    float* obuf = (float*)(wsb + 26214400);         //  3,686,400 B
    bf16*  wb2b = (bf16*) (wsb + 29900800);         //  1,179,648 B
    bf16*  wbb  = (bf16*) (wsb + 31080448);         //    589,824 B
    float* wTof = (float*)(wsb + 31670272);         //    165,888 B

    hipLaunchKernelGGL(k_wdprep,    dim3(2304), dim3(256), 0, stream, wd, wb2b);
    hipLaunchKernelGGL(k_wprep,     dim3(1152), dim3(256), 0, stream, w1, wbb);
    hipLaunchKernelGGL(k_woprep2,   dim3(162),  dim3(256), 0, stream, wo, wTof);
    hipLaunchKernelGGL(k_conv1,     dim3(800),  dim3(256), 0, stream, x, wbb, g1, b1, m1, v1, hNb);
    hipLaunchKernelGGL(k_off_v,     dim3(800),  dim3(256), 0, stream, hNb, wTof, bo, obuf);
    hipLaunchKernelGGL(k_dconv_nhwc,dim3(800),  dim3(256), 0, stream, hNb, obuf, wb2b, g2, b2, m2, v2, outp);
}

// Round 8
// 624.129 us; speedup vs baseline: 2.8506x; 1.1710x over previous
//
#include <hip/hip_runtime.h>
#include <hip/hip_bf16.h>

// DCNConv pipeline, MI355X round 7: conv1 -> NHWC-x tap-major staging (the
// validated dconv recipe); x transposed to NHWC bf16 by k_xprep.
// Fallback to the validated round-6 configuration if ws < 84.3 MB.
//
// Primary ws layout (84,264,960 B):
//   [0)          hN   bf16 [8][6400pix][256c] = 26,214,400 B
//   [26,214,400) off  fp32 [8][18][6400]      =  3,686,400 B
//   [29,900,800) wb2  bf16 [256][2304]        =  1,179,648 B (dconv w, tap-major)
//   [31,080,448) wb1  bf16 [256][1152]        =    589,824 B (conv1 w; primary: tap-major, fallback: c-major)
//   [31,670,272) wToff fp32 [9][256][18]      =    165,888 B (off w, transposed)
//   [31,836,160) xN   bf16 [8][25600pix][128c]= 52,428,800 B

typedef __hip_bfloat16 bf16;
typedef __attribute__((ext_vector_type(8))) short short8;
typedef __attribute__((ext_vector_type(4))) float float4v;

#define EPSBN 1e-5f

__device__ __forceinline__ float bf2f(bf16 x){ return __bfloat162float(x); }
__device__ __forceinline__ float bits2f(unsigned short u){ return __uint_as_float(((unsigned)u) << 16); }
__device__ __forceinline__ float silu_(float x){ return x / (1.f + __expf(-x)); }
__device__ __forceinline__ unsigned short f2bf_bits(float f){
    union { float f; unsigned u; } uf; uf.f = f;
    unsigned r = uf.u + 0x7fff + ((uf.u >> 16) & 1);   // RNE (finite inputs)
    return (unsigned short)(r >> 16);
}

// ---------------------------------------------------------------------------
// K0a: dconv_w [256oc][256c][9tap] fp32 -> wb2 bf16 [256oc][2304], kk = tap*256+c.
__global__ __launch_bounds__(256) void k_wdprep(const float* __restrict__ w, bf16* __restrict__ wb2)
{
    int idx = blockIdx.x * 256 + threadIdx.x;
    if (idx >= 256 * 2304) return;
    int oc  = idx / 2304;
    int r   = idx - oc * 2304;
    int tap = r >> 8;
    int c   = r & 255;
    wb2[idx] = __float2bfloat16(w[(oc * 256 + c) * 9 + tap]);
}

// K0b (primary): conv1 weights -> bf16 TAP-MAJOR [oc][tap*128+c].
__global__ __launch_bounds__(256) void k_wprep1t(const float* __restrict__ w, bf16* __restrict__ wb)
{
    int idx = blockIdx.x * 256 + threadIdx.x;      // 294,912
    if (idx >= 256 * 1152) return;
    int oc  = idx / 1152;
    int r   = idx - oc * 1152;
    int tap = r >> 7;
    int c   = r & 127;
    wb[idx] = __float2bfloat16(w[(oc * 128 + c) * 9 + tap]);
}

// K0b' (fallback): conv1 weights -> bf16, c-major [oc][c*9+tap] (round-6).
__global__ __launch_bounds__(256) void k_wprep(const float* __restrict__ w, bf16* __restrict__ wb)
{
    int idx = blockIdx.x * 256 + threadIdx.x;
    if (idx >= 256 * 1152) return;
    wb[idx] = __float2bfloat16(w[idx]);
}

// K0c: off_w [18oc][256c][9tap] fp32 -> wToff fp32 [(tap*256+c)*18 + oc].
__global__ __launch_bounds__(256) void k_woprep2(const float* __restrict__ w, float* __restrict__ wT)
{
    int idx = blockIdx.x * 256 + threadIdx.x;      // 41,472
    if (idx >= 9 * 256 * 18) return;
    int oc  = idx % 18;
    int r   = idx / 18;
    int c   = r & 255;
    int tap = r >> 8;
    wT[idx] = w[(oc * 256 + c) * 9 + tap];
}

// K0d: x NCHW fp32 -> xN NHWC bf16 via LDS tile transpose.
// Block = 64 pixels x 128 channels. Read: lane = pixel (coalesced 256 B).
// Write: 32 threads/pixel, ushort4 -> 512 B contiguous per wave.
__global__ __launch_bounds__(256) void k_xprep(const float* __restrict__ x, bf16* __restrict__ xN)
{
    __shared__ short sm[64 * 132];                 // 16,896 B (stride 132: 264 B, 8B-aligned rows)
    const int tid  = threadIdx.x;
    const int b    = blockIdx.x / 400;             // 3200 blocks
    const int pix0 = (blockIdx.x % 400) * 64;
    const int lane = tid & 63;
    const int wq   = tid >> 6;
    const float* xb = x + (size_t)b * 128 * 25600;

    #pragma unroll
    for (int i = 0; i < 32; i++){
        int c = i * 4 + wq;
        sm[lane * 132 + c] = (short)f2bf_bits(xb[c * 25600 + pix0 + lane]);
    }
    __syncthreads();

    bf16* xo = xN + ((size_t)b * 25600 + pix0) * 128;
    #pragma unroll
    for (int j = 0; j < 8; j++){
        int idx = j * 256 + tid;                   // 0..2047
        int p = idx >> 5, q = idx & 31;
        *reinterpret_cast<ushort4*>(xo + p * 128 + q * 4) =
            *reinterpret_cast<const ushort4*>(&sm[p * 132 + q * 4]);
    }
}

// ---------------------------------------------------------------------------
// K1 (primary): conv1 (3x3 s2 p1) + BN1 + SiLU, MFMA implicit GEMM on NHWC xN.
// K = 1152 tap-major (kk = tap*128+c), 36 chunks = 9 taps x 4 subs.
// Source pixel per (tap, out-pixel) is integer: precompute idx+mask once.
// Stage B: thread = (pixel t4, ch-quad cq): 2 masked ushort4 loads (contiguous
// channels) -> ushort4 LDS writes. Identical fragment/epilogue to validated.
__global__ __launch_bounds__(256) void k_conv1n(
    const bf16* __restrict__ xN, const bf16* __restrict__ wb,
    const float* __restrict__ g, const float* __restrict__ bb,
    const float* __restrict__ mm, const float* __restrict__ vv,
    bf16* __restrict__ hN)
{
    __shared__ short A_lds[256 * 40];              // 20,480 B
    __shared__ short B_lds[64 * 40];               //  5,120 B
    __shared__ unsigned short nidx[576];           //  1,152 B
    __shared__ unsigned short nmsk[576];           //  1,152 B
    __shared__ float sc_s[256], sh_s[256];         //  2,048 B

    const int tid  = threadIdx.x;
    const int b    = blockIdx.x / 100;             // 800 blocks
    const int pix0 = (blockIdx.x % 100) * 64;
    const bf16* xb = xN + (size_t)b * 25600 * 128;

    {
        float scv = g[tid] * rsqrtf(vv[tid] + EPSBN);
        sc_s[tid] = scv;
        sh_s[tid] = bb[tid] - mm[tid] * scv;
    }

    // source pixel per (tap, out-pixel): ih = 2*oh+kh-1 (<=159 always; mask >=0 only)
    for (int e = tid; e < 576; e += 256){
        int t = e & 63, k = e >> 6;
        int pix = pix0 + t;
        int oh = pix / 80, ow = pix % 80;
        int ih = 2 * oh + k / 3 - 1;
        int iw = 2 * ow + k % 3 - 1;
        nmsk[e] = ((ih | iw) >= 0) ? 1 : 0;
        nidx[e] = (unsigned short)(max(ih, 0) * 160 + max(iw, 0));
    }
    __syncthreads();

    const int t4   = tid >> 2;                     // pixel 0..63
    const int cq   = tid & 3;                      // channel quad
    const int wv   = tid >> 6;
    const int lane = tid & 63;
    const int lrow = lane & 15;
    const int quad = lane >> 4;

    float4v acc[4][4];
    #pragma unroll
    for (int i = 0; i < 4; i++)
        #pragma unroll
        for (int j = 0; j < 4; j++)
            acc[i][j] = (float4v){0.f, 0.f, 0.f, 0.f};

    for (int kc = 0; kc < 36; kc++){
        const int tap = kc >> 2;
        const int cb  = (kc & 3) * 32;
        __syncthreads();

        // stage A: 256oc x 32k
        #pragma unroll
        for (int p2 = 0; p2 < 4; p2++){
            int idx = p2 * 256 + tid;
            int oc  = idx >> 2;
            int kq  = idx & 3;
            *reinterpret_cast<uint4*>(&A_lds[oc * 40 + kq * 8]) =
                *reinterpret_cast<const uint4*>(wb + oc * 1152 + kc * 32 + kq * 8);
        }

        // stage B: 64pos x 32c, contiguous-channel ushort4 loads
        {
            const int e  = tap * 64 + t4;
            const int sp = (int)nidx[e];
            const bool mv = nmsk[e] != 0;
            const bf16* xp = xb + (size_t)sp * 128 + cb;
            #pragma unroll
            for (int p = 0; p < 2; p++){
                int kci0 = cq * 4 + p * 16;
                ushort4 v = {0, 0, 0, 0};
                if (mv) v = *reinterpret_cast<const ushort4*>(xp + kci0);
                *reinterpret_cast<ushort4*>(&B_lds[t4 * 40 + kci0]) = v;
            }
        }
        __syncthreads();

        short8 af[4], bfv[4];
        #pragma unroll
        for (int i = 0; i < 4; i++){
            int row = wv * 64 + i * 16 + lrow;
            af[i] = *reinterpret_cast<const short8*>(&A_lds[row * 40 + quad * 8]);
        }
        #pragma unroll
        for (int j = 0; j < 4; j++){
            bfv[j] = *reinterpret_cast<const short8*>(&B_lds[(j * 16 + lrow) * 40 + quad * 8]);
        }
        #pragma unroll
        for (int i = 0; i < 4; i++)
            #pragma unroll
            for (int j = 0; j < 4; j++)
                acc[i][j] = __builtin_amdgcn_mfma_f32_16x16x32_bf16(af[i], bfv[j], acc[i][j], 0, 0, 0);
    }

    #pragma unroll
    for (int i = 0; i < 4; i++){
        int oc0 = wv * 64 + i * 16 + quad * 4;
        float s0 = sc_s[oc0+0], h0 = sh_s[oc0+0];
        float s1 = sc_s[oc0+1], h1 = sh_s[oc0+1];
        float s2 = sc_s[oc0+2], h2 = sh_s[oc0+2];
        float s3 = sc_s[oc0+3], h3 = sh_s[oc0+3];
        #pragma unroll
        for (int j = 0; j < 4; j++){
            int pix = pix0 + j * 16 + lrow;
            ushort4 o;
            o.x = f2bf_bits(silu_(acc[i][j][0] * s0 + h0));
            o.y = f2bf_bits(silu_(acc[i][j][1] * s1 + h1));
            o.z = f2bf_bits(silu_(acc[i][j][2] * s2 + h2));
            o.w = f2bf_bits(silu_(acc[i][j][3] * s3 + h3));
            *reinterpret_cast<ushort4*>(hN + ((size_t)b * 6400 + pix) * 256 + oc0) = o;
        }
    }
}

// K1 (fallback): round-6 conv1 on NCHW fp32 x (validated), verbatim.
__global__ __launch_bounds__(256) void k_conv1(
    const float* __restrict__ x, const bf16* __restrict__ wb,
    const float* __restrict__ g, const float* __restrict__ bb,
    const float* __restrict__ mm, const float* __restrict__ vv,
    bf16* __restrict__ hN)
{
    __shared__ short A_lds[256 * 40];
    __shared__ short B_lds[64 * 40];
    __shared__ float sc_s[256], sh_s[256];

    const int tid  = threadIdx.x;
    const int b    = blockIdx.x / 100;
    const int pix0 = (blockIdx.x % 100) * 64;
    const float* xb = x + b * (128 * 25600);

    {
        float scv = g[tid] * rsqrtf(vv[tid] + EPSBN);
        sc_s[tid] = scv;
        sh_s[tid] = bb[tid] - mm[tid] * scv;
    }

    const int k_in = tid & 31;
    const int prow = tid >> 5;
    int oh8[8], ow8[8];
    #pragma unroll
    for (int p = 0; p < 8; p++){
        int pix = pix0 + prow + p * 8;
        oh8[p] = pix / 80; ow8[p] = pix % 80;
    }

    const int wv   = tid >> 6;
    const int lane = tid & 63;
    const int lrow = lane & 15;
    const int quad = lane >> 4;

    float4v acc[4][4];
    #pragma unroll
    for (int i = 0; i < 4; i++)
        #pragma unroll
        for (int j = 0; j < 4; j++)
            acc[i][j] = (float4v){0.f, 0.f, 0.f, 0.f};

    for (int kc = 0; kc < 36; kc++){
        const int k0 = kc * 32;
        __syncthreads();

        #pragma unroll
        for (int p2 = 0; p2 < 4; p2++){
            int idx = p2 * 256 + tid;
            int oc  = idx >> 2;
            int kq  = idx & 3;
            *reinterpret_cast<uint4*>(&A_lds[oc * 40 + kq * 8]) =
                *reinterpret_cast<const uint4*>(wb + oc * 1152 + k0 + kq * 8);
        }

        {
            int kk  = k0 + k_in;
            int c   = kk / 9;
            int tap = kk - 9 * c;
            int kh  = tap / 3 - 1;
            int kw  = tap - 3 * (tap / 3) - 1;
            const float* xc = xb + c * 25600;
            #pragma unroll
            for (int p = 0; p < 8; p++){
                int ih = 2 * oh8[p] + kh;
                int iw = 2 * ow8[p] + kw;
                float v = 0.f;
                if ((ih | iw) >= 0) v = xc[ih * 160 + iw];
                B_lds[(prow + p * 8) * 40 + k_in] = (short)f2bf_bits(v);
            }
        }
        __syncthreads();

        short8 af[4], bfv[4];
        #pragma unroll
        for (int i = 0; i < 4; i++){
            int row = wv * 64 + i * 16 + lrow;
            af[i] = *reinterpret_cast<const short8*>(&A_lds[row * 40 + quad * 8]);
        }
        #pragma unroll
        for (int j = 0; j < 4; j++){
            bfv[j] = *reinterpret_cast<const short8*>(&B_lds[(j * 16 + lrow) * 40 + quad * 8]);
        }
        #pragma unroll
        for (int i = 0; i < 4; i++)
            #pragma unroll
            for (int j = 0; j < 4; j++)
                acc[i][j] = __builtin_amdgcn_mfma_f32_16x16x32_bf16(af[i], bfv[j], acc[i][j], 0, 0, 0);
    }

    #pragma unroll
    for (int i = 0; i < 4; i++){
        int oc0 = wv * 64 + i * 16 + quad * 4;
        float s0 = sc_s[oc0+0], h0 = sh_s[oc0+0];
        float s1 = sc_s[oc0+1], h1 = sh_s[oc0+1];
        float s2 = sc_s[oc0+2], h2 = sh_s[oc0+2];
        float s3 = sc_s[oc0+3], h3 = sh_s[oc0+3];
        #pragma unroll
        for (int j = 0; j < 4; j++){
            int pix = pix0 + j * 16 + lrow;
            ushort4 o;
            o.x = f2bf_bits(silu_(acc[i][j][0] * s0 + h0));
            o.y = f2bf_bits(silu_(acc[i][j][1] * s1 + h1));
            o.z = f2bf_bits(silu_(acc[i][j][2] * s2 + h2));
            o.w = f2bf_bits(silu_(acc[i][j][3] * s3 + h3));
            *reinterpret_cast<ushort4*>(hN + (b * 6400 + pix) * 256 + oc0) = o;
        }
    }
}

// ---------------------------------------------------------------------------
// K2: offset conv, vectorized VALU on NHWC h (validated round 6, verbatim).
__global__ __launch_bounds__(256) void k_off_v(
    const bf16* __restrict__ hN, const float* __restrict__ wT,
    const float* __restrict__ bias, float* __restrict__ off)
{
    __shared__ float red[4 * 18 * 64];

    const int tid   = threadIdx.x;
    const int b     = blockIdx.x / 100;
    const int pix0  = (blockIdx.x % 100) * 64;
    const int lane  = tid & 63;
    const int wv    = tid >> 6;
    const int cbase = __builtin_amdgcn_readfirstlane(wv << 6);

    const int pix = pix0 + lane;
    const int oh  = pix / 80, ow = pix % 80;

    float acc[18];
    #pragma unroll
    for (int o = 0; o < 18; o++) acc[o] = 0.f;

    for (int tap = 0; tap < 9; tap++){
        int ih = oh + tap / 3 - 1, iw = ow + tap % 3 - 1;
        bool val = ((unsigned)ih < 80u) && ((unsigned)iw < 80u);
        int  sp  = min(max(ih, 0), 79) * 80 + min(max(iw, 0), 79);
        float m  = val ? 1.f : 0.f;
        const bf16*  hp = hN + (size_t)(b * 6400 + sp) * 256 + cbase;
        const float* wp = wT + (tap * 256 + cbase) * 18;
        for (int cs = 0; cs < 64; cs += 4){
            ushort4 hv = *reinterpret_cast<const ushort4*>(hp + cs);
            float h0 = bits2f(hv.x) * m, h1 = bits2f(hv.y) * m,
                  h2 = bits2f(hv.z) * m, h3 = bits2f(hv.w) * m;
            const float* w0 = wp + cs * 18;
            #pragma unroll
            for (int o = 0; o < 18; o++){
                acc[o] += h0 * w0[o] + h1 * w0[18 + o] + h2 * w0[36 + o] + h3 * w0[54 + o];
            }
        }
    }

    #pragma unroll
    for (int o = 0; o < 18; o++)
        red[(wv * 18 + o) * 64 + lane] = acc[o];
    __syncthreads();

    for (int i = tid; i < 18 * 64; i += 256){
        int o = i >> 6, p = i & 63;
        float s = red[(0 * 18 + o) * 64 + p] + red[(1 * 18 + o) * 64 + p]
                + red[(2 * 18 + o) * 64 + p] + red[(3 * 18 + o) * 64 + p] + bias[o];
        off[(b * 18 + o) * 6400 + pix0 + p] = s;
    }
}

// ---------------------------------------------------------------------------
// K3: deform conv MFMA on NHWC h (validated round 5, verbatim).
__global__ __launch_bounds__(256) void k_dconv_nhwc(
    const bf16* __restrict__ hN, const float* __restrict__ off,
    const bf16* __restrict__ wb2,
    const float* __restrict__ g, const float* __restrict__ bb,
    const float* __restrict__ mm, const float* __restrict__ vv,
    float* __restrict__ out)
{
    __shared__ short   A_lds[256 * 40];
    __shared__ short   B_lds[64 * 40];
    __shared__ ushort4 sidxu[576];
    __shared__ ushort4 swtu [576];
    __shared__ float   sc_s[256], sh_s[256];

    const int tid  = threadIdx.x;
    const int b    = blockIdx.x / 100;
    const int pix0 = (blockIdx.x % 100) * 64;
    const bf16* hb = hN + b * (6400 * 256);

    {
        float scv = g[tid] * rsqrtf(vv[tid] + EPSBN);
        sc_s[tid] = scv;
        sh_s[tid] = bb[tid] - mm[tid] * scv;
    }

    for (int e = tid; e < 576; e += 256){
        int t = e & 63, k = e >> 6;
        int pix = pix0 + t;
        int oh = pix / 80, ow = pix % 80;
        int kh = k / 3, kw = k % 3;
        float oy = off[(b * 18 + 2 * k    ) * 6400 + pix];
        float ox = off[(b * 18 + 2 * k + 1) * 6400 + pix];
        float py = (float)(oh + kh - 1) + oy;
        float px = (float)(ow + kw - 1) + ox;
        float y0f = floorf(py), x0f = floorf(px);
        float wy1 = py - y0f,  wx1 = px - x0f;
        int y0 = (int)y0f, x0 = (int)x0f;
        unsigned short ii[4], ww[4];
        #pragma unroll
        for (int cy = 0; cy < 2; cy++){
            int   yy = y0 + cy;
            float wy = cy ? wy1 : 1.f - wy1;
            bool  vy = (yy >= 0) && (yy < 80);
            int   yc = min(max(yy, 0), 79);
            #pragma unroll
            for (int cx = 0; cx < 2; cx++){
                int   xx = x0 + cx;
                float wx = cx ? wx1 : 1.f - wx1;
                bool  vx = (xx >= 0) && (xx < 80);
                int   xc = min(max(xx, 0), 79);
                int ci = cy * 2 + cx;
                ii[ci] = (unsigned short)(yc * 80 + xc);
                ww[ci] = f2bf_bits((vy && vx) ? wy * wx : 0.f);
            }
        }
        ushort4 iv; iv.x = ii[0]; iv.y = ii[1]; iv.z = ii[2]; iv.w = ii[3];
        ushort4 wv_; wv_.x = ww[0]; wv_.y = ww[1]; wv_.z = ww[2]; wv_.w = ww[3];
        sidxu[e] = iv;
        swtu [e] = wv_;
    }
    __syncthreads();

    const int t4   = tid >> 2;
    const int cq   = tid & 3;
    const int wv   = tid >> 6;
    const int lane = tid & 63;
    const int lrow = lane & 15;
    const int quad = lane >> 4;

    float4v acc[4][4];
    #pragma unroll
    for (int i = 0; i < 4; i++)
        #pragma unroll
        for (int j = 0; j < 4; j++)
            acc[i][j] = (float4v){0.f, 0.f, 0.f, 0.f};

    for (int tap = 0; tap < 9; tap++){
        const int e = tap * 64 + t4;
        ushort4 ipk = sidxu[e];
        ushort4 wpk = swtu[e];
        const float w0 = bits2f(wpk.x), w1 = bits2f(wpk.y),
                    w2 = bits2f(wpk.z), w3 = bits2f(wpk.w);
        const int i0 = (int)ipk.x * 256, i1 = (int)ipk.y * 256,
                  i2 = (int)ipk.z * 256, i3 = (int)ipk.w * 256;

        for (int sub = 0; sub < 8; sub++){
            const int kc = tap * 8 + sub;
            __syncthreads();

            #pragma unroll
            for (int p2 = 0; p2 < 4; p2++){
                int idx = p2 * 256 + tid;
                int oc  = idx >> 2;
                int kq  = idx & 3;
                *reinterpret_cast<uint4*>(&A_lds[oc * 40 + kq * 8]) =
                    *reinterpret_cast<const uint4*>(wb2 + oc * 2304 + kc * 32 + kq * 8);
            }

            {
                const int cb = sub * 32;
                #pragma unroll
                for (int p = 0; p < 2; p++){
                    int kci0 = cq * 4 + p * 16;
                    int co   = cb + kci0;
                    ushort4 ca = *reinterpret_cast<const ushort4*>(hb + i0 + co);
                    ushort4 cbv= *reinterpret_cast<const ushort4*>(hb + i1 + co);
                    ushort4 cc = *reinterpret_cast<const ushort4*>(hb + i2 + co);
                    ushort4 cd = *reinterpret_cast<const ushort4*>(hb + i3 + co);
                    ushort4 o;
                    o.x = f2bf_bits(w0*bits2f(ca.x) + w1*bits2f(cbv.x) + w2*bits2f(cc.x) + w3*bits2f(cd.x));
                    o.y = f2bf_bits(w0*bits2f(ca.y) + w1*bits2f(cbv.y) + w2*bits2f(cc.y) + w3*bits2f(cd.y));
                    o.z = f2bf_bits(w0*bits2f(ca.z) + w1*bits2f(cbv.z) + w2*bits2f(cc.z) + w3*bits2f(cd.z));
                    o.w = f2bf_bits(w0*bits2f(ca.w) + w1*bits2f(cbv.w) + w2*bits2f(cc.w) + w3*bits2f(cd.w));
                    *reinterpret_cast<ushort4*>(&B_lds[t4 * 40 + kci0]) = o;
                }
            }
            __syncthreads();

            short8 af[4], bfv[4];
            #pragma unroll
            for (int i = 0; i < 4; i++){
                int row = wv * 64 + i * 16 + lrow;
                af[i] = *reinterpret_cast<const short8*>(&A_lds[row * 40 + quad * 8]);
            }
            #pragma unroll
            for (int j = 0; j < 4; j++){
                bfv[j] = *reinterpret_cast<const short8*>(&B_lds[(j * 16 + lrow) * 40 + quad * 8]);
            }
            #pragma unroll
            for (int i = 0; i < 4; i++)
                #pragma unroll
                for (int j = 0; j < 4; j++)
                    acc[i][j] = __builtin_amdgcn_mfma_f32_16x16x32_bf16(af[i], bfv[j], acc[i][j], 0, 0, 0);
        }
    }

    #pragma unroll
    for (int i = 0; i < 4; i++){
        #pragma unroll
        for (int r = 0; r < 4; r++){
            int oc = wv * 64 + i * 16 + quad * 4 + r;
            float scv = sc_s[oc], shv = sh_s[oc];
            #pragma unroll
            for (int j = 0; j < 4; j++){
                int pix = pix0 + j * 16 + lrow;
                out[(b * 256 + oc) * 6400 + pix] = silu_(acc[i][j][r] * scv + shv);
            }
        }
    }
}

// ---------------------------------------------------------------------------
extern "C" void kernel_launch(void* const* d_in, const int* in_sizes, int n_in,
                              void* d_out, int out_size, void* d_ws, size_t ws_size,
                              hipStream_t stream)
{
    (void)in_sizes; (void)n_in; (void)out_size;

    const float* x  = (const float*)d_in[0];
    const float* w1 = (const float*)d_in[1];
    const float* g1 = (const float*)d_in[2];
    const float* b1 = (const float*)d_in[3];
    const float* m1 = (const float*)d_in[4];
    const float* v1 = (const float*)d_in[5];
    const float* wo = (const float*)d_in[6];
    const float* bo = (const float*)d_in[7];
    const float* wd = (const float*)d_in[8];
    const float* g2 = (const float*)d_in[9];
    const float* b2 = (const float*)d_in[10];
    const float* m2 = (const float*)d_in[11];
    const float* v2 = (const float*)d_in[12];
    float* outp = (float*)d_out;

    char*  wsb  = (char*)d_ws;
    bf16*  hNb  = (bf16*) wsb;                      // 26,214,400 B
    float* obuf = (float*)(wsb + 26214400);         //  3,686,400 B
    bf16*  wb2b = (bf16*) (wsb + 29900800);         //  1,179,648 B
    bf16*  wbb  = (bf16*) (wsb + 31080448);         //    589,824 B
    float* wTof = (float*)(wsb + 31670272);         //    165,888 B
    bf16*  xNb  = (bf16*) (wsb + 31836160);         // 52,428,800 B

    const size_t need_primary = 84264960;

    hipLaunchKernelGGL(k_wdprep,  dim3(2304), dim3(256), 0, stream, wd, wb2b);
    hipLaunchKernelGGL(k_woprep2, dim3(162),  dim3(256), 0, stream, wo, wTof);

    if (ws_size >= need_primary){
        hipLaunchKernelGGL(k_wprep1t, dim3(1152), dim3(256), 0, stream, w1, wbb);
        hipLaunchKernelGGL(k_xprep,   dim3(3200), dim3(256), 0, stream, x, xNb);
        hipLaunchKernelGGL(k_conv1n,  dim3(800),  dim3(256), 0, stream, xNb, wbb, g1, b1, m1, v1, hNb);
    } else {
        hipLaunchKernelGGL(k_wprep,   dim3(1152), dim3(256), 0, stream, w1, wbb);
        hipLaunchKernelGGL(k_conv1,   dim3(800),  dim3(256), 0, stream, x, wbb, g1, b1, m1, v1, hNb);
    }

    hipLaunchKernelGGL(k_off_v,     dim3(800), dim3(256), 0, stream, hNb, wTof, bo, obuf);
    hipLaunchKernelGGL(k_dconv_nhwc,dim3(800), dim3(256), 0, stream, hNb, obuf, wb2b, g2, b2, m2, v2, outp);
}